// Round 10
// baseline (191.258 us; speedup 1.0000x reference)
//
#include <hip/hip_runtime.h>

#define N_NODES 50000
#define N_PANELS 3125            // 50000 / 16 exactly
#define N_EDGES 300000
#define EPS_F 1e-12f
#define EB ((N_EDGES + 255) / 256)        // 1172 edge-blocks
#define GRID 1024                         // gemm grid (grid-stride over panels)
#define SCAN_NB ((N_NODES + 255) / 256)   // 196
#define MASK48 ((1ull << 48) - 1)
#define ZBYTES (N_NODES * 20)             // pk_out(8) + pk_in(8) + cur(4)

typedef _Float16 f16x8 __attribute__((ext_vector_type(8)));
typedef float f32x4 __attribute__((ext_vector_type(4)));

static __device__ inline f32x4 mfma_f16(f16x8 a, f16x8 b, f32x4 c) {
    return __builtin_amdgcn_mfma_f32_16x16x32_f16(a, b, c, 0, 0, 0);
}

// fragment-ready swizzled layout for a [R][256] f16 matrix:
// element (row, k) at ((row>>4)*8 + (k>>5))*512 + ((k>>3)&3)*128 + (row&15)*8 + (k&7)
static __device__ inline size_t swz(int row, int l) {
    return ((size_t)(row >> 4) * 8 + (l >> 2)) * 512 + (size_t)((l & 3) * 128 + (row & 15) * 8);
}

// ---------------------------------------------------------------------------
// Workspace zero-init
// ---------------------------------------------------------------------------

__global__ __launch_bounds__(256) void zero_kernel(int4* __restrict__ p, int n16) {
    int i = blockIdx.x * 256 + threadIdx.x;
    if (i < n16) p[i] = make_int4(0, 0, 0, 0);
}

// ---------------------------------------------------------------------------
// P1: deg (packed fixed-point atomics) ∥ wsplit (W -> swizzled f16 fragments)
// ---------------------------------------------------------------------------

__global__ __launch_bounds__(256) void p1_kernel(const int* __restrict__ ei,
                                                 const float* __restrict__ ew,
                                                 unsigned long long* __restrict__ pk_out,
                                                 unsigned long long* __restrict__ pk_in,
                                                 const float* __restrict__ W6,
                                                 const float* __restrict__ W7,
                                                 const float* __restrict__ Wp,
                                                 _Float16* __restrict__ Bsw) {
    int b = blockIdx.x;
    if (b < EB) {
        int e = b * 256 + threadIdx.x;
        if (e >= N_EDGES) return;
        int s = ei[e];
        int d = ei[N_EDGES + e];
        unsigned long long wfx = (unsigned long long)(ew[e] * 4294967296.0f);
        atomicAdd(&pk_out[s], wfx);
        atomicAdd(&pk_in[d], (1ull << 48) | wfx);
    } else {
        int bb = b - EB;                  // 0..95
        int wsel = bb >> 5;               // 0..2
        const float* W = (wsel == 0) ? W6 : (wsel == 1) ? W7 : Wp;
        int id = (bb & 31) * 256 + threadIdx.x;   // 0..8191
        int n = id >> 5, l = id & 31;
        f16x8 o;
#pragma unroll
        for (int j = 0; j < 8; ++j)
            o[j] = (_Float16)W[(l * 8 + j) * 256 + n];
        *(f16x8*)&Bsw[(size_t)wsel * 65536 + swz(n, l)] = o;
    }
}

// --- scan: per-block reduce, then fused (partial-scan + local scan) ---------

__global__ __launch_bounds__(256) void scan1_kernel(const unsigned long long* __restrict__ pk_in,
                                                    const unsigned long long* __restrict__ pk_out,
                                                    float* __restrict__ deg_in,
                                                    float* __restrict__ deg_out,
                                                    int* __restrict__ partial) {
    __shared__ int sh[256];
    int i = blockIdx.x * 256 + threadIdx.x;
    int c = 0;
    if (i < N_NODES) {
        unsigned long long p = pk_in[i];
        c = (int)(p >> 48);
        deg_in[i] = (float)(p & MASK48) * 0x1p-32f;
        deg_out[i] = (float)pk_out[i] * 0x1p-32f;
    }
    sh[threadIdx.x] = c;
    __syncthreads();
    for (int off = 128; off > 0; off >>= 1) {
        if (threadIdx.x < (unsigned)off) sh[threadIdx.x] += sh[threadIdx.x + off];
        __syncthreads();
    }
    if (threadIdx.x == 0) partial[blockIdx.x] = sh[0];
}

// fused scan2+scan3: every block redundantly scans the 196 partials (trivial)
__global__ __launch_bounds__(256) void scan23_kernel(const unsigned long long* __restrict__ pk_in,
                                                     const int* __restrict__ partial,
                                                     int* __restrict__ row_ptr) {
    __shared__ int ps[256];
    __shared__ int sh[256];
    int t = threadIdx.x;
    int pv = (t < SCAN_NB) ? partial[t] : 0;
    ps[t] = pv;
    __syncthreads();
    for (int off = 1; off < 256; off <<= 1) {
        int x = (t >= off) ? ps[t - off] : 0;
        __syncthreads();
        ps[t] += x;
        __syncthreads();
    }
    int incl = ps[t];
    __syncthreads();
    ps[t] = incl - pv;    // exclusive prefix of partials
    __syncthreads();
    const int boff = ps[blockIdx.x];

    int i = blockIdx.x * 256 + t;
    int v = (i < N_NODES) ? (int)(pk_in[i] >> 48) : 0;
    sh[t] = v;
    __syncthreads();
    for (int off = 1; off < 256; off <<= 1) {
        int x = (t >= off) ? sh[t - off] : 0;
        __syncthreads();
        sh[t] += x;
        __syncthreads();
    }
    if (i < N_NODES) row_ptr[i] = sh[t] - v + boff;
    if (i == 0) row_ptr[N_NODES] = N_EDGES;
}

// fill (fused norm): one packed {src, norm} store per CSR slot
__global__ void fill_kernel(const int* __restrict__ ei, const float* __restrict__ ew,
                            const float* __restrict__ deg_out, const float* __restrict__ deg_in,
                            const int* __restrict__ row_ptr, int* __restrict__ cur,
                            int2* __restrict__ csr) {
    int e = blockIdx.x * blockDim.x + threadIdx.x;
    if (e >= N_EDGES) return;
    int s = ei[e];
    int d = ei[N_EDGES + e];
    float nm = ew[e] * rsqrtf(deg_out[s] * deg_in[d] + EPS_F);
    int pos = atomicAdd(&cur[d], 1);
    csr[row_ptr[d] + pos] = make_int2(s, __float_as_int(nm));
}

// ---------------------------------------------------------------------------
// gemm_h5: layer-1 GEMM reading h5 f32 row-major directly (conversion fused),
// B-frags in VGPRs, f16 row-major xt out via LDS bounce. No barriers.
// ---------------------------------------------------------------------------

__global__ __launch_bounds__(256) void gemm_h5(const float* __restrict__ h5,
                                               const _Float16* __restrict__ Bsw,
                                               _Float16* __restrict__ xt) {
    __shared__ __align__(16) _Float16 ebuf[4][16 * 72];

    const int t = threadIdx.x;
    const int w = t >> 6, lane = t & 63;

    f16x8 bf[4][8];
#pragma unroll
    for (int cp4 = 0; cp4 < 4; ++cp4)
#pragma unroll
        for (int kb = 0; kb < 8; ++kb)
            bf[cp4][kb] = *(const f16x8*)&Bsw[(size_t)((w * 4 + cp4) * 8 + kb) * 512 + lane * 8];

    for (int p = blockIdx.x; p < N_PANELS; p += GRID) {
        const float* ab = &h5[(size_t)(p * 16 + (lane & 15)) * 256 + (lane >> 4) * 8];
        f16x8 af[8];
#pragma unroll
        for (int kb = 0; kb < 8; ++kb) {
            float4 v0 = *(const float4*)(ab + kb * 32);
            float4 v1 = *(const float4*)(ab + kb * 32 + 4);
            f16x8 a;
            a[0] = (_Float16)v0.x; a[1] = (_Float16)v0.y;
            a[2] = (_Float16)v0.z; a[3] = (_Float16)v0.w;
            a[4] = (_Float16)v1.x; a[5] = (_Float16)v1.y;
            a[6] = (_Float16)v1.z; a[7] = (_Float16)v1.w;
            af[kb] = a;
        }

        f32x4 acc[4];
#pragma unroll
        for (int cp4 = 0; cp4 < 4; ++cp4) acc[cp4] = (f32x4){0.f, 0.f, 0.f, 0.f};
#pragma unroll
        for (int kb = 0; kb < 8; ++kb)
#pragma unroll
            for (int cp4 = 0; cp4 < 4; ++cp4)
                acc[cp4] = mfma_f16(af[kb], bf[cp4][kb], acc[cp4]);

        // D: row = 4*(lane>>4)+reg, col = lane&15  [m89-verified]
        _Float16* eb = ebuf[w];
        const int rq = 4 * (lane >> 4);
        const int lr = lane & 15;
#pragma unroll
        for (int cp4 = 0; cp4 < 4; ++cp4)
#pragma unroll
            for (int rr = 0; rr < 4; ++rr)
                eb[(rq + rr) * 72 + cp4 * 16 + lr] = (_Float16)acc[cp4][rr];
#pragma unroll
        for (int it = 0; it < 2; ++it) {
            int rl = it * 8 + (lane >> 3);
            f16x8 v = *(const f16x8*)&eb[rl * 72 + (lane & 7) * 8];
            *(f16x8*)&xt[(size_t)(p * 16 + rl) * 256 + w * 64 + (lane & 7) * 8] = v;
        }
    }
}

// ---------------------------------------------------------------------------
// gemm (swizzled f16 A): MODE 0 -> f16 row-major xt; MODE 1 -> f32 + bias out
// (MODE 1 epilogue bounces f32 through LDS for 256B-per-row coalesced stores)
// ---------------------------------------------------------------------------

template <int MODE>
__global__ __launch_bounds__(256) void gemm_f16(const _Float16* __restrict__ Asw,
                                                const _Float16* __restrict__ Bsw,
                                                const float* __restrict__ bias,
                                                void* __restrict__ Cout) {
    __shared__ __align__(16) char ebraw[4][16 * 68 * 4];   // fits f16x72 & f32x68

    const int t = threadIdx.x;
    const int w = t >> 6, lane = t & 63;
    const int lr = lane & 15;

    f16x8 bf[4][8];
#pragma unroll
    for (int cp4 = 0; cp4 < 4; ++cp4)
#pragma unroll
        for (int kb = 0; kb < 8; ++kb)
            bf[cp4][kb] = *(const f16x8*)&Bsw[(size_t)((w * 4 + cp4) * 8 + kb) * 512 + lane * 8];

    float bc[4];
    if (MODE == 1) {
#pragma unroll
        for (int cp4 = 0; cp4 < 4; ++cp4) bc[cp4] = bias[w * 64 + cp4 * 16 + lr];
    }

    for (int p = blockIdx.x; p < N_PANELS; p += GRID) {
        const _Float16* abase = &Asw[(size_t)p * 4096 + lane * 8];
        f16x8 af[8];
#pragma unroll
        for (int kb = 0; kb < 8; ++kb)
            af[kb] = *(const f16x8*)&abase[kb * 512];

        f32x4 acc[4];
#pragma unroll
        for (int cp4 = 0; cp4 < 4; ++cp4) acc[cp4] = (f32x4){0.f, 0.f, 0.f, 0.f};
#pragma unroll
        for (int kb = 0; kb < 8; ++kb)
#pragma unroll
            for (int cp4 = 0; cp4 < 4; ++cp4)
                acc[cp4] = mfma_f16(af[kb], bf[cp4][kb], acc[cp4]);

        const int rq = 4 * (lane >> 4);
        if (MODE == 0) {
            _Float16* eb = (_Float16*)ebraw[w];
#pragma unroll
            for (int cp4 = 0; cp4 < 4; ++cp4)
#pragma unroll
                for (int rr = 0; rr < 4; ++rr)
                    eb[(rq + rr) * 72 + cp4 * 16 + lr] = (_Float16)acc[cp4][rr];
            _Float16* xp = (_Float16*)Cout;
#pragma unroll
            for (int it = 0; it < 2; ++it) {
                int rl = it * 8 + (lane >> 3);
                f16x8 v = *(const f16x8*)&eb[rl * 72 + (lane & 7) * 8];
                *(f16x8*)&xp[(size_t)(p * 16 + rl) * 256 + w * 64 + (lane & 7) * 8] = v;
            }
        } else {
            float* eb = (float*)ebraw[w];
#pragma unroll
            for (int cp4 = 0; cp4 < 4; ++cp4)
#pragma unroll
                for (int rr = 0; rr < 4; ++rr)
                    eb[(rq + rr) * 68 + cp4 * 16 + lr] = acc[cp4][rr] + bc[cp4];
            float* op = (float*)Cout;
#pragma unroll
            for (int it = 0; it < 4; ++it) {
                int rl = it * 4 + (lane >> 4);
                float4 v = *(const float4*)&eb[rl * 68 + lr * 4];
                *(float4*)&op[(size_t)(p * 16 + rl) * 256 + w * 64 + lr * 4] = v;
            }
        }
    }
}

// ---------------------------------------------------------------------------
// Aggregation: 8 nodes/block, 32 lanes/node, 8 features/lane, 8 gathers in
// flight (λ≈6 → usually one predicated 7-wide round); packed {src,norm}.
// ---------------------------------------------------------------------------

__global__ __launch_bounds__(256) void agg_kernel(const _Float16* __restrict__ xt,
                                                  const int* __restrict__ row_ptr,
                                                  const int2* __restrict__ csr,
                                                  const float* __restrict__ bias,
                                                  _Float16* __restrict__ Asw) {
    const int g = threadIdx.x >> 5;
    const int l = threadIdx.x & 31;
    const int v = blockIdx.x * 8 + g;
    const int d0 = l * 8;

    const int s0 = row_ptr[v];
    const int s1 = row_ptr[v + 1];

    float acc[8] = {0.f, 0.f, 0.f, 0.f, 0.f, 0.f, 0.f, 0.f};

    int i = s0;
    for (; i + 8 <= s1; i += 8) {
        int2 hd[8];
#pragma unroll
        for (int u = 0; u < 8; ++u) hd[u] = csr[i + u];
        f16x8 val[8];
#pragma unroll
        for (int u = 0; u < 8; ++u)
            val[u] = *(const f16x8*)&xt[(size_t)hd[u].x * 256 + d0];
#pragma unroll
        for (int u = 0; u < 8; ++u) {
            float wv = __int_as_float(hd[u].y);
#pragma unroll
            for (int j = 0; j < 8; ++j)
                acc[j] += (float)val[u][j] * wv;
        }
    }
    int rem = s1 - i;   // 0..7
    if (rem) {
        int2 hd[7];
#pragma unroll
        for (int u = 0; u < 7; ++u)
            hd[u] = (u < rem) ? csr[i + u] : make_int2(0, 0);
        f16x8 val[7];
#pragma unroll
        for (int u = 0; u < 7; ++u)
            val[u] = *(const f16x8*)&xt[(size_t)hd[u].x * 256 + d0];
#pragma unroll
        for (int u = 0; u < 7; ++u) {
            float wv = __int_as_float(hd[u].y);
#pragma unroll
            for (int j = 0; j < 8; ++j)
                acc[j] += (float)val[u][j] * wv;
        }
    }

    f16x8 o;
#pragma unroll
    for (int j = 0; j < 8; ++j) {
        float r = acc[j] + bias[d0 + j];
        r = r > 0.f ? r : 0.f;
        o[j] = (_Float16)r;
    }
    *(f16x8*)&Asw[swz(v, l)] = o;
}

// ---------------------------------------------------------------------------

extern "C" void kernel_launch(void* const* d_in, const int* in_sizes, int n_in,
                              void* d_out, int out_size, void* d_ws, size_t ws_size,
                              hipStream_t stream) {
    (void)in_sizes; (void)n_in; (void)out_size; (void)ws_size;
    const float* h5 = (const float*)d_in[0];
    const int*   ei = (const int*)d_in[1];
    const float* ew = (const float*)d_in[2];
    const float* W6 = (const float*)d_in[3];
    const float* b6 = (const float*)d_in[4];
    const float* W7 = (const float*)d_in[5];
    const float* b7 = (const float*)d_in[6];
    const float* Wp = (const float*)d_in[7];
    const float* bp = (const float*)d_in[8];
    float* out = (float*)d_out;

    char* ws = (char*)d_ws;
    size_t off = 0;
    auto alloc = [&](size_t bytes) -> void* {
        void* p = ws + off;
        off = (off + bytes + 255) & ~(size_t)255;
        return p;
    };

    // single zeroed region: pk_out | pk_in | cur
    char* zblk = (char*)alloc(ZBYTES);
    unsigned long long* pk_out = (unsigned long long*)zblk;
    unsigned long long* pk_in  = (unsigned long long*)(zblk + N_NODES * 8);
    int* cur = (int*)(zblk + N_NODES * 16);

    float* deg_out = (float*)alloc(N_NODES * 4);
    float* deg_in  = (float*)alloc(N_NODES * 4);
    int*   row_ptr = (int*)alloc((N_NODES + 1) * 4);
    int*   partial = (int*)alloc(SCAN_NB * 4);
    int2*  csr     = (int2*)alloc(N_EDGES * 8);
    _Float16* Bsw  = (_Float16*)alloc(3 * 65536 * 2);
    _Float16* Asw  = (_Float16*)alloc((size_t)N_NODES * 256 * 2);
    _Float16* xt   = (_Float16*)alloc((size_t)N_NODES * 256 * 2);

    const int Z16 = ZBYTES / 16;

    zero_kernel<<<(Z16 + 255) / 256, 256, 0, stream>>>((int4*)zblk, Z16);

    // deg ∥ wsplit
    p1_kernel<<<EB + 96, 256, 0, stream>>>(ei, ew, pk_out, pk_in, W6, W7, Wp, Bsw);

    // layer-1 GEMM (independent of graph prep; reads h5 f32 directly)
    gemm_h5<<<GRID, 256, 0, stream>>>(h5, Bsw, xt);

    scan1_kernel<<<SCAN_NB, 256, 0, stream>>>(pk_in, pk_out, deg_in, deg_out, partial);
    scan23_kernel<<<SCAN_NB, 256, 0, stream>>>(pk_in, partial, row_ptr);
    fill_kernel<<<EB, 256, 0, stream>>>(ei, ew, deg_out, deg_in, row_ptr, cur, csr);

    agg_kernel<<<N_NODES / 8, 256, 0, stream>>>(xt, row_ptr, csr, b6, Asw);
    gemm_f16<0><<<GRID, 256, 0, stream>>>(Asw, Bsw + 65536, nullptr, xt);
    agg_kernel<<<N_NODES / 8, 256, 0, stream>>>(xt, row_ptr, csr, b7, Asw);
    gemm_f16<1><<<GRID, 256, 0, stream>>>(Asw, Bsw + 2 * 65536, bp, out);
}

// Round 11
// 166.519 us; speedup vs baseline: 1.1486x; 1.1486x over previous
//
#include <hip/hip_runtime.h>

#define N_NODES 50000
#define N_PANELS 3125            // 50000 / 16 exactly
#define N_EDGES 300000
#define EPS_F 1e-12f
#define EB ((N_EDGES + 255) / 256)        // 1172 edge-blocks
#define WB 96                             // wsplit blocks
#define AB (N_NODES * 32 / 256)           // 6250 asplit blocks
#define GB 512                            // gemm grid (grid-stride over panels)
#define SCAN_NB ((N_NODES + 255) / 256)   // 196
#define MASK48 ((1ull << 48) - 1)
#define ZBYTES (N_NODES * 20)             // pk_out(8) + pk_in(8) + cur(4)

typedef _Float16 f16x8 __attribute__((ext_vector_type(8)));
typedef float f32x4 __attribute__((ext_vector_type(4)));

static __device__ inline f32x4 mfma_f16(f16x8 a, f16x8 b, f32x4 c) {
    return __builtin_amdgcn_mfma_f32_16x16x32_f16(a, b, c, 0, 0, 0);
}

// fragment-ready swizzled layout for a [R][256] f16 matrix:
// element (row, k) at ((row>>4)*8 + (k>>5))*512 + ((k>>3)&3)*128 + (row&15)*8 + (k&7)
static __device__ inline size_t swz(int row, int l) {
    return ((size_t)(row >> 4) * 8 + (l >> 2)) * 512 + (size_t)((l & 3) * 128 + (row & 15) * 8);
}

// ---------------------------------------------------------------------------
// Workspace zero-init
// ---------------------------------------------------------------------------

__global__ __launch_bounds__(256) void zero_kernel(int4* __restrict__ p, int n16) {
    int i = blockIdx.x * 256 + threadIdx.x;
    if (i < n16) p[i] = make_int4(0, 0, 0, 0);
}

// ---------------------------------------------------------------------------
// P1: deg (packed fixed-point atomics) ∥ wsplit ∥ asplit (h5 -> swizzled f16)
// deg is atomic-latency-bound; the conversions are BW-bound -> free overlap.
// ---------------------------------------------------------------------------

__global__ __launch_bounds__(256) void p1_kernel(const int* __restrict__ ei,
                                                 const float* __restrict__ ew,
                                                 unsigned long long* __restrict__ pk_out,
                                                 unsigned long long* __restrict__ pk_in,
                                                 const float* __restrict__ W6,
                                                 const float* __restrict__ W7,
                                                 const float* __restrict__ Wp,
                                                 _Float16* __restrict__ Bsw,
                                                 const float* __restrict__ h5,
                                                 _Float16* __restrict__ Asw) {
    int b = blockIdx.x;
    if (b < EB) {
        int e = b * 256 + threadIdx.x;
        if (e >= N_EDGES) return;
        int s = ei[e];
        int d = ei[N_EDGES + e];
        unsigned long long wfx = (unsigned long long)(ew[e] * 4294967296.0f);
        atomicAdd(&pk_out[s], wfx);
        atomicAdd(&pk_in[d], (1ull << 48) | wfx);
    } else if (b < EB + WB) {
        int bb = b - EB;                  // 0..95
        int wsel = bb >> 5;               // 0..2
        const float* W = (wsel == 0) ? W6 : (wsel == 1) ? W7 : Wp;
        int id = (bb & 31) * 256 + threadIdx.x;   // 0..8191
        int n = id >> 5, l = id & 31;
        f16x8 o;
#pragma unroll
        for (int j = 0; j < 8; ++j)
            o[j] = (_Float16)W[(l * 8 + j) * 256 + n];
        *(f16x8*)&Bsw[(size_t)wsel * 65536 + swz(n, l)] = o;
    } else {
        int tid = (b - EB - WB) * 256 + threadIdx.x;   // 0 .. 1,600,000 exact
        int row = tid >> 5, l = tid & 31;
        const float* p = &h5[(size_t)row * 256 + l * 8];
        float4 v0 = *(const float4*)p;
        float4 v1 = *(const float4*)(p + 4);
        f16x8 o;
        o[0] = (_Float16)v0.x; o[1] = (_Float16)v0.y;
        o[2] = (_Float16)v0.z; o[3] = (_Float16)v0.w;
        o[4] = (_Float16)v1.x; o[5] = (_Float16)v1.y;
        o[6] = (_Float16)v1.z; o[7] = (_Float16)v1.w;
        *(f16x8*)&Asw[swz(row, l)] = o;
    }
}

// --- scan: per-block reduce, then fused (partial-scan + local scan) ---------

__global__ __launch_bounds__(256) void scan1_kernel(const unsigned long long* __restrict__ pk_in,
                                                    const unsigned long long* __restrict__ pk_out,
                                                    float* __restrict__ deg_in,
                                                    float* __restrict__ deg_out,
                                                    int* __restrict__ partial) {
    __shared__ int sh[256];
    int i = blockIdx.x * 256 + threadIdx.x;
    int c = 0;
    if (i < N_NODES) {
        unsigned long long p = pk_in[i];
        c = (int)(p >> 48);
        deg_in[i] = (float)(p & MASK48) * 0x1p-32f;
        deg_out[i] = (float)pk_out[i] * 0x1p-32f;
    }
    sh[threadIdx.x] = c;
    __syncthreads();
    for (int off = 128; off > 0; off >>= 1) {
        if (threadIdx.x < (unsigned)off) sh[threadIdx.x] += sh[threadIdx.x + off];
        __syncthreads();
    }
    if (threadIdx.x == 0) partial[blockIdx.x] = sh[0];
}

// fused scan2+scan3: every block redundantly scans the 196 partials (trivial)
__global__ __launch_bounds__(256) void scan23_kernel(const unsigned long long* __restrict__ pk_in,
                                                     const int* __restrict__ partial,
                                                     int* __restrict__ row_ptr) {
    __shared__ int ps[256];
    __shared__ int sh[256];
    int t = threadIdx.x;
    int pv = (t < SCAN_NB) ? partial[t] : 0;
    ps[t] = pv;
    __syncthreads();
    for (int off = 1; off < 256; off <<= 1) {
        int x = (t >= off) ? ps[t - off] : 0;
        __syncthreads();
        ps[t] += x;
        __syncthreads();
    }
    int incl = ps[t];
    __syncthreads();
    ps[t] = incl - pv;    // exclusive prefix of partials
    __syncthreads();
    const int boff = ps[blockIdx.x];

    int i = blockIdx.x * 256 + t;
    int v = (i < N_NODES) ? (int)(pk_in[i] >> 48) : 0;
    sh[t] = v;
    __syncthreads();
    for (int off = 1; off < 256; off <<= 1) {
        int x = (t >= off) ? sh[t - off] : 0;
        __syncthreads();
        sh[t] += x;
        __syncthreads();
    }
    if (i < N_NODES) row_ptr[i] = sh[t] - v + boff;
    if (i == 0) row_ptr[N_NODES] = N_EDGES;
}

// ---------------------------------------------------------------------------
// P2: fill (fused norm, packed {src,norm} CSR) ∥ gemm layer-1 (swizzled A).
// fill is atomic-latency-bound; gemm streams under it.
// ---------------------------------------------------------------------------

__global__ __launch_bounds__(256) void p2_kernel(const int* __restrict__ ei,
                                                 const float* __restrict__ ew,
                                                 const float* __restrict__ deg_out,
                                                 const float* __restrict__ deg_in,
                                                 const int* __restrict__ row_ptr,
                                                 int* __restrict__ cur,
                                                 int2* __restrict__ csr,
                                                 const _Float16* __restrict__ Asw,
                                                 const _Float16* __restrict__ Bsw,
                                                 _Float16* __restrict__ xt) {
    __shared__ __align__(16) _Float16 ebuf[4][16 * 72];

    if (blockIdx.x < EB) {
        int e = blockIdx.x * 256 + threadIdx.x;
        if (e >= N_EDGES) return;
        int s = ei[e];
        int d = ei[N_EDGES + e];
        float nm = ew[e] * rsqrtf(deg_out[s] * deg_in[d] + EPS_F);
        int pos = atomicAdd(&cur[d], 1);
        csr[row_ptr[d] + pos] = make_int2(s, __float_as_int(nm));
        return;
    }

    const int t = threadIdx.x;
    const int w = t >> 6, lane = t & 63;

    f16x8 bf[4][8];
#pragma unroll
    for (int cp4 = 0; cp4 < 4; ++cp4)
#pragma unroll
        for (int kb = 0; kb < 8; ++kb)
            bf[cp4][kb] = *(const f16x8*)&Bsw[(size_t)((w * 4 + cp4) * 8 + kb) * 512 + lane * 8];

    for (int p = blockIdx.x - EB; p < N_PANELS; p += GB) {
        const _Float16* abase = &Asw[(size_t)p * 4096 + lane * 8];
        f16x8 af[8];
#pragma unroll
        for (int kb = 0; kb < 8; ++kb)
            af[kb] = *(const f16x8*)&abase[kb * 512];

        f32x4 acc[4];
#pragma unroll
        for (int cp4 = 0; cp4 < 4; ++cp4) acc[cp4] = (f32x4){0.f, 0.f, 0.f, 0.f};
#pragma unroll
        for (int kb = 0; kb < 8; ++kb)
#pragma unroll
            for (int cp4 = 0; cp4 < 4; ++cp4)
                acc[cp4] = mfma_f16(af[kb], bf[cp4][kb], acc[cp4]);

        // D: row = 4*(lane>>4)+reg, col = lane&15  [m89-verified]
        _Float16* eb = ebuf[w];
        const int rq = 4 * (lane >> 4);
        const int lr = lane & 15;
#pragma unroll
        for (int cp4 = 0; cp4 < 4; ++cp4)
#pragma unroll
            for (int rr = 0; rr < 4; ++rr)
                eb[(rq + rr) * 72 + cp4 * 16 + lr] = (_Float16)acc[cp4][rr];
#pragma unroll
        for (int it = 0; it < 2; ++it) {
            int rl = it * 8 + (lane >> 3);
            f16x8 v = *(const f16x8*)&eb[rl * 72 + (lane & 7) * 8];
            *(f16x8*)&xt[(size_t)(p * 16 + rl) * 256 + w * 64 + (lane & 7) * 8] = v;
        }
    }
}

// ---------------------------------------------------------------------------
// gemm (swizzled f16 A): MODE 0 -> f16 row-major xt; MODE 1 -> f32 + bias out
// (MODE 1 epilogue bounces f32 through LDS for 256B-per-row coalesced stores)
// ---------------------------------------------------------------------------

template <int MODE>
__global__ __launch_bounds__(256) void gemm_f16(const _Float16* __restrict__ Asw,
                                                const _Float16* __restrict__ Bsw,
                                                const float* __restrict__ bias,
                                                void* __restrict__ Cout) {
    __shared__ __align__(16) char ebraw[4][16 * 68 * 4];   // fits f16x72 & f32x68

    const int t = threadIdx.x;
    const int w = t >> 6, lane = t & 63;
    const int lr = lane & 15;

    f16x8 bf[4][8];
#pragma unroll
    for (int cp4 = 0; cp4 < 4; ++cp4)
#pragma unroll
        for (int kb = 0; kb < 8; ++kb)
            bf[cp4][kb] = *(const f16x8*)&Bsw[(size_t)((w * 4 + cp4) * 8 + kb) * 512 + lane * 8];

    float bc[4];
    if (MODE == 1) {
#pragma unroll
        for (int cp4 = 0; cp4 < 4; ++cp4) bc[cp4] = bias[w * 64 + cp4 * 16 + lr];
    }

    for (int p = blockIdx.x; p < N_PANELS; p += GB) {
        const _Float16* abase = &Asw[(size_t)p * 4096 + lane * 8];
        f16x8 af[8];
#pragma unroll
        for (int kb = 0; kb < 8; ++kb)
            af[kb] = *(const f16x8*)&abase[kb * 512];

        f32x4 acc[4];
#pragma unroll
        for (int cp4 = 0; cp4 < 4; ++cp4) acc[cp4] = (f32x4){0.f, 0.f, 0.f, 0.f};
#pragma unroll
        for (int kb = 0; kb < 8; ++kb)
#pragma unroll
            for (int cp4 = 0; cp4 < 4; ++cp4)
                acc[cp4] = mfma_f16(af[kb], bf[cp4][kb], acc[cp4]);

        const int rq = 4 * (lane >> 4);
        if (MODE == 0) {
            _Float16* eb = (_Float16*)ebraw[w];
#pragma unroll
            for (int cp4 = 0; cp4 < 4; ++cp4)
#pragma unroll
                for (int rr = 0; rr < 4; ++rr)
                    eb[(rq + rr) * 72 + cp4 * 16 + lr] = (_Float16)acc[cp4][rr];
            _Float16* xp = (_Float16*)Cout;
#pragma unroll
            for (int it = 0; it < 2; ++it) {
                int rl = it * 8 + (lane >> 3);
                f16x8 v = *(const f16x8*)&eb[rl * 72 + (lane & 7) * 8];
                *(f16x8*)&xp[(size_t)(p * 16 + rl) * 256 + w * 64 + (lane & 7) * 8] = v;
            }
        } else {
            float* eb = (float*)ebraw[w];
#pragma unroll
            for (int cp4 = 0; cp4 < 4; ++cp4)
#pragma unroll
                for (int rr = 0; rr < 4; ++rr)
                    eb[(rq + rr) * 68 + cp4 * 16 + lr] = acc[cp4][rr] + bc[cp4];
            float* op = (float*)Cout;
#pragma unroll
            for (int it = 0; it < 4; ++it) {
                int rl = it * 4 + (lane >> 4);
                float4 v = *(const float4*)&eb[rl * 68 + lr * 4];
                *(float4*)&op[(size_t)(p * 16 + rl) * 256 + w * 64 + lr * 4] = v;
            }
        }
    }
}

// ---------------------------------------------------------------------------
// Aggregation: 8 nodes/block, 32 lanes/node, 8 features/lane, 4 gathers in
// flight; packed {src,norm} headers; writes fragment-swizzled f16 output.
// ---------------------------------------------------------------------------

__global__ __launch_bounds__(256) void agg_kernel(const _Float16* __restrict__ xt,
                                                  const int* __restrict__ row_ptr,
                                                  const int2* __restrict__ csr,
                                                  const float* __restrict__ bias,
                                                  _Float16* __restrict__ Asw) {
    const int g = threadIdx.x >> 5;
    const int l = threadIdx.x & 31;
    const int v = blockIdx.x * 8 + g;
    const int d0 = l * 8;

    const int s0 = row_ptr[v];
    const int s1 = row_ptr[v + 1];

    float acc[8] = {0.f, 0.f, 0.f, 0.f, 0.f, 0.f, 0.f, 0.f};

    int i = s0;
    for (; i + 4 <= s1; i += 4) {
        int2 hd[4];
#pragma unroll
        for (int u = 0; u < 4; ++u) hd[u] = csr[i + u];
        f16x8 val[4];
#pragma unroll
        for (int u = 0; u < 4; ++u)
            val[u] = *(const f16x8*)&xt[(size_t)hd[u].x * 256 + d0];
#pragma unroll
        for (int u = 0; u < 4; ++u) {
            float wv = __int_as_float(hd[u].y);
#pragma unroll
            for (int j = 0; j < 8; ++j)
                acc[j] += (float)val[u][j] * wv;
        }
    }
    {
        int rem = s1 - i;
        int2 hd[3];
#pragma unroll
        for (int u = 0; u < 3; ++u)
            hd[u] = (u < rem) ? csr[i + u] : make_int2(0, 0);
        f16x8 val[3];
#pragma unroll
        for (int u = 0; u < 3; ++u)
            val[u] = *(const f16x8*)&xt[(size_t)hd[u].x * 256 + d0];
#pragma unroll
        for (int u = 0; u < 3; ++u) {
            float wv = __int_as_float(hd[u].y);
#pragma unroll
            for (int j = 0; j < 8; ++j)
                acc[j] += (float)val[u][j] * wv;
        }
    }

    f16x8 o;
#pragma unroll
    for (int j = 0; j < 8; ++j) {
        float r = acc[j] + bias[d0 + j];
        r = r > 0.f ? r : 0.f;
        o[j] = (_Float16)r;
    }
    *(f16x8*)&Asw[swz(v, l)] = o;
}

// ---------------------------------------------------------------------------

extern "C" void kernel_launch(void* const* d_in, const int* in_sizes, int n_in,
                              void* d_out, int out_size, void* d_ws, size_t ws_size,
                              hipStream_t stream) {
    (void)in_sizes; (void)n_in; (void)out_size; (void)ws_size;
    const float* h5 = (const float*)d_in[0];
    const int*   ei = (const int*)d_in[1];
    const float* ew = (const float*)d_in[2];
    const float* W6 = (const float*)d_in[3];
    const float* b6 = (const float*)d_in[4];
    const float* W7 = (const float*)d_in[5];
    const float* b7 = (const float*)d_in[6];
    const float* Wp = (const float*)d_in[7];
    const float* bp = (const float*)d_in[8];
    float* out = (float*)d_out;

    char* ws = (char*)d_ws;
    size_t off = 0;
    auto alloc = [&](size_t bytes) -> void* {
        void* p = ws + off;
        off = (off + bytes + 255) & ~(size_t)255;
        return p;
    };

    // single zeroed region: pk_out | pk_in | cur
    char* zblk = (char*)alloc(ZBYTES);
    unsigned long long* pk_out = (unsigned long long*)zblk;
    unsigned long long* pk_in  = (unsigned long long*)(zblk + N_NODES * 8);
    int* cur = (int*)(zblk + N_NODES * 16);

    float* deg_out = (float*)alloc(N_NODES * 4);
    float* deg_in  = (float*)alloc(N_NODES * 4);
    int*   row_ptr = (int*)alloc((N_NODES + 1) * 4);
    int*   partial = (int*)alloc(SCAN_NB * 4);
    int2*  csr     = (int2*)alloc(N_EDGES * 8);
    _Float16* Bsw  = (_Float16*)alloc(3 * 65536 * 2);
    _Float16* Asw  = (_Float16*)alloc((size_t)N_NODES * 256 * 2);
    _Float16* xt   = (_Float16*)alloc((size_t)N_NODES * 256 * 2);

    const int Z16 = ZBYTES / 16;

    zero_kernel<<<(Z16 + 255) / 256, 256, 0, stream>>>((int4*)zblk, Z16);

    // deg ∥ wsplit ∥ asplit
    p1_kernel<<<EB + WB + AB, 256, 0, stream>>>(ei, ew, pk_out, pk_in,
                                                W6, W7, Wp, Bsw, h5, Asw);

    scan1_kernel<<<SCAN_NB, 256, 0, stream>>>(pk_in, pk_out, deg_in, deg_out, partial);
    scan23_kernel<<<SCAN_NB, 256, 0, stream>>>(pk_in, partial, row_ptr);

    // fill ∥ gemm layer-1 (swizzled f16 A)
    p2_kernel<<<EB + GB, 256, 0, stream>>>(ei, ew, deg_out, deg_in, row_ptr, cur, csr,
                                           Asw, Bsw, xt);

    agg_kernel<<<N_NODES / 8, 256, 0, stream>>>(xt, row_ptr, csr, b6, Asw);
    gemm_f16<0><<<GB, 256, 0, stream>>>(Asw, Bsw + 65536, nullptr, xt);
    agg_kernel<<<N_NODES / 8, 256, 0, stream>>>(xt, row_ptr, csr, b7, Asw);
    gemm_f16<1><<<GB, 256, 0, stream>>>(Asw, Bsw + 2 * 65536, bp, out);
}

// Round 12
// 162.405 us; speedup vs baseline: 1.1777x; 1.0253x over previous
//
#include <hip/hip_runtime.h>

#define N_NODES 50000
#define N_PANELS 3125            // 50000 / 16 exactly
#define N_EDGES 300000
#define EPS_F 1e-12f
#define DEGB 64                           // compact deg blocks (grid-stride)
#define WB 96                             // wsplit blocks
#define AB (N_NODES * 32 / 256)           // 6250 asplit blocks
#define FILLB 128                         // compact fill blocks (grid-stride)
#define GB 512                            // gemm grid (grid-stride over panels)
#define SCAN_NB ((N_NODES + 255) / 256)   // 196
#define MASK48 ((1ull << 48) - 1)
#define ZBYTES (N_NODES * 20)             // pk_out(8) + pk_in(8) + cur(4)

typedef _Float16 f16x8 __attribute__((ext_vector_type(8)));
typedef float f32x4 __attribute__((ext_vector_type(4)));

static __device__ inline f32x4 mfma_f16(f16x8 a, f16x8 b, f32x4 c) {
    return __builtin_amdgcn_mfma_f32_16x16x32_f16(a, b, c, 0, 0, 0);
}

// fragment-ready swizzled layout for a [R][256] f16 matrix:
// element (row, k) at ((row>>4)*8 + (k>>5))*512 + ((k>>3)&3)*128 + (row&15)*8 + (k&7)
static __device__ inline size_t swz(int row, int l) {
    return ((size_t)(row >> 4) * 8 + (l >> 2)) * 512 + (size_t)((l & 3) * 128 + (row & 15) * 8);
}

// ---------------------------------------------------------------------------
// Workspace zero-init
// ---------------------------------------------------------------------------

__global__ __launch_bounds__(256) void zero_kernel(int4* __restrict__ p, int n16) {
    int i = blockIdx.x * 256 + threadIdx.x;
    if (i < n16) p[i] = make_int4(0, 0, 0, 0);
}

// ---------------------------------------------------------------------------
// P1: deg (64 compact blocks, fire-and-forget packed atomics) ∥ wsplit ∥
// asplit. Compact deg leaves ~97% of block slots to the BW-bound conversions.
// ---------------------------------------------------------------------------

__global__ __launch_bounds__(256) void p1_kernel(const int* __restrict__ ei,
                                                 const float* __restrict__ ew,
                                                 unsigned long long* __restrict__ pk_out,
                                                 unsigned long long* __restrict__ pk_in,
                                                 const float* __restrict__ W6,
                                                 const float* __restrict__ W7,
                                                 const float* __restrict__ Wp,
                                                 _Float16* __restrict__ Bsw,
                                                 const float* __restrict__ h5,
                                                 _Float16* __restrict__ Asw) {
    int b = blockIdx.x;
    if (b < DEGB) {
        // fire-and-forget atomics: no return -> no dependent waitcnt, deep queue
        for (int e = b * 256 + (int)threadIdx.x; e < N_EDGES; e += DEGB * 256) {
            int s = ei[e];
            int d = ei[N_EDGES + e];
            unsigned long long wfx = (unsigned long long)(ew[e] * 4294967296.0f);
            atomicAdd(&pk_out[s], wfx);
            atomicAdd(&pk_in[d], (1ull << 48) | wfx);
        }
    } else if (b < DEGB + WB) {
        int bb = b - DEGB;                // 0..95
        int wsel = bb >> 5;               // 0..2
        const float* W = (wsel == 0) ? W6 : (wsel == 1) ? W7 : Wp;
        int id = (bb & 31) * 256 + threadIdx.x;   // 0..8191
        int n = id >> 5, l = id & 31;
        f16x8 o;
#pragma unroll
        for (int j = 0; j < 8; ++j)
            o[j] = (_Float16)W[(l * 8 + j) * 256 + n];
        *(f16x8*)&Bsw[(size_t)wsel * 65536 + swz(n, l)] = o;
    } else {
        int tid = (b - DEGB - WB) * 256 + threadIdx.x;   // 0 .. 1,600,000 exact
        int row = tid >> 5, l = tid & 31;
        const float* p = &h5[(size_t)row * 256 + l * 8];
        float4 v0 = *(const float4*)p;
        float4 v1 = *(const float4*)(p + 4);
        f16x8 o;
        o[0] = (_Float16)v0.x; o[1] = (_Float16)v0.y;
        o[2] = (_Float16)v0.z; o[3] = (_Float16)v0.w;
        o[4] = (_Float16)v1.x; o[5] = (_Float16)v1.y;
        o[6] = (_Float16)v1.z; o[7] = (_Float16)v1.w;
        *(f16x8*)&Asw[swz(row, l)] = o;
    }
}

// --- scan: per-block reduce, then fused (partial-scan + local scan) ---------

__global__ __launch_bounds__(256) void scan1_kernel(const unsigned long long* __restrict__ pk_in,
                                                    const unsigned long long* __restrict__ pk_out,
                                                    float* __restrict__ deg_in,
                                                    float* __restrict__ deg_out,
                                                    int* __restrict__ partial) {
    __shared__ int sh[256];
    int i = blockIdx.x * 256 + threadIdx.x;
    int c = 0;
    if (i < N_NODES) {
        unsigned long long p = pk_in[i];
        c = (int)(p >> 48);
        deg_in[i] = (float)(p & MASK48) * 0x1p-32f;
        deg_out[i] = (float)pk_out[i] * 0x1p-32f;
    }
    sh[threadIdx.x] = c;
    __syncthreads();
    for (int off = 128; off > 0; off >>= 1) {
        if (threadIdx.x < (unsigned)off) sh[threadIdx.x] += sh[threadIdx.x + off];
        __syncthreads();
    }
    if (threadIdx.x == 0) partial[blockIdx.x] = sh[0];
}

// fused scan2+scan3: every block redundantly scans the 196 partials (trivial)
__global__ __launch_bounds__(256) void scan23_kernel(const unsigned long long* __restrict__ pk_in,
                                                     const int* __restrict__ partial,
                                                     int* __restrict__ row_ptr) {
    __shared__ int ps[256];
    __shared__ int sh[256];
    int t = threadIdx.x;
    int pv = (t < SCAN_NB) ? partial[t] : 0;
    ps[t] = pv;
    __syncthreads();
    for (int off = 1; off < 256; off <<= 1) {
        int x = (t >= off) ? ps[t - off] : 0;
        __syncthreads();
        ps[t] += x;
        __syncthreads();
    }
    int incl = ps[t];
    __syncthreads();
    ps[t] = incl - pv;    // exclusive prefix of partials
    __syncthreads();
    const int boff = ps[blockIdx.x];

    int i = blockIdx.x * 256 + t;
    int v = (i < N_NODES) ? (int)(pk_in[i] >> 48) : 0;
    sh[t] = v;
    __syncthreads();
    for (int off = 1; off < 256; off <<= 1) {
        int x = (t >= off) ? sh[t - off] : 0;
        __syncthreads();
        sh[t] += x;
        __syncthreads();
    }
    if (i < N_NODES) row_ptr[i] = sh[t] - v + boff;
    if (i == 0) row_ptr[N_NODES] = N_EDGES;
}

// ---------------------------------------------------------------------------
// P2: fill (128 compact grid-strided blocks) ∥ gemm layer-1 (swizzled A).
// ---------------------------------------------------------------------------

__global__ __launch_bounds__(256) void p2_kernel(const int* __restrict__ ei,
                                                 const float* __restrict__ ew,
                                                 const float* __restrict__ deg_out,
                                                 const float* __restrict__ deg_in,
                                                 const int* __restrict__ row_ptr,
                                                 int* __restrict__ cur,
                                                 int2* __restrict__ csr,
                                                 const _Float16* __restrict__ Asw,
                                                 const _Float16* __restrict__ Bsw,
                                                 _Float16* __restrict__ xt) {
    __shared__ __align__(16) _Float16 ebuf[4][16 * 72];

    if (blockIdx.x < FILLB) {
        for (int e = blockIdx.x * 256 + (int)threadIdx.x; e < N_EDGES; e += FILLB * 256) {
            int s = ei[e];
            int d = ei[N_EDGES + e];
            float nm = ew[e] * rsqrtf(deg_out[s] * deg_in[d] + EPS_F);
            int pos = atomicAdd(&cur[d], 1);
            csr[row_ptr[d] + pos] = make_int2(s, __float_as_int(nm));
        }
        return;
    }

    const int t = threadIdx.x;
    const int w = t >> 6, lane = t & 63;

    f16x8 bf[4][8];
#pragma unroll
    for (int cp4 = 0; cp4 < 4; ++cp4)
#pragma unroll
        for (int kb = 0; kb < 8; ++kb)
            bf[cp4][kb] = *(const f16x8*)&Bsw[(size_t)((w * 4 + cp4) * 8 + kb) * 512 + lane * 8];

    for (int p = blockIdx.x - FILLB; p < N_PANELS; p += GB) {
        const _Float16* abase = &Asw[(size_t)p * 4096 + lane * 8];
        f16x8 af[8];
#pragma unroll
        for (int kb = 0; kb < 8; ++kb)
            af[kb] = *(const f16x8*)&abase[kb * 512];

        f32x4 acc[4];
#pragma unroll
        for (int cp4 = 0; cp4 < 4; ++cp4) acc[cp4] = (f32x4){0.f, 0.f, 0.f, 0.f};
#pragma unroll
        for (int kb = 0; kb < 8; ++kb)
#pragma unroll
            for (int cp4 = 0; cp4 < 4; ++cp4)
                acc[cp4] = mfma_f16(af[kb], bf[cp4][kb], acc[cp4]);

        // D: row = 4*(lane>>4)+reg, col = lane&15  [m89-verified]
        _Float16* eb = ebuf[w];
        const int rq = 4 * (lane >> 4);
        const int lr = lane & 15;
#pragma unroll
        for (int cp4 = 0; cp4 < 4; ++cp4)
#pragma unroll
            for (int rr = 0; rr < 4; ++rr)
                eb[(rq + rr) * 72 + cp4 * 16 + lr] = (_Float16)acc[cp4][rr];
#pragma unroll
        for (int it = 0; it < 2; ++it) {
            int rl = it * 8 + (lane >> 3);
            f16x8 v = *(const f16x8*)&eb[rl * 72 + (lane & 7) * 8];
            *(f16x8*)&xt[(size_t)(p * 16 + rl) * 256 + w * 64 + (lane & 7) * 8] = v;
        }
    }
}

// ---------------------------------------------------------------------------
// gemm (swizzled f16 A): MODE 0 -> f16 row-major xt; MODE 1 -> f32 + bias out
// (MODE 1 epilogue bounces f32 through LDS for 256B-per-row coalesced stores)
// ---------------------------------------------------------------------------

template <int MODE>
__global__ __launch_bounds__(256) void gemm_f16(const _Float16* __restrict__ Asw,
                                                const _Float16* __restrict__ Bsw,
                                                const float* __restrict__ bias,
                                                void* __restrict__ Cout) {
    __shared__ __align__(16) char ebraw[4][16 * 68 * 4];   // fits f16x72 & f32x68

    const int t = threadIdx.x;
    const int w = t >> 6, lane = t & 63;
    const int lr = lane & 15;

    f16x8 bf[4][8];
#pragma unroll
    for (int cp4 = 0; cp4 < 4; ++cp4)
#pragma unroll
        for (int kb = 0; kb < 8; ++kb)
            bf[cp4][kb] = *(const f16x8*)&Bsw[(size_t)((w * 4 + cp4) * 8 + kb) * 512 + lane * 8];

    float bc[4];
    if (MODE == 1) {
#pragma unroll
        for (int cp4 = 0; cp4 < 4; ++cp4) bc[cp4] = bias[w * 64 + cp4 * 16 + lr];
    }

    for (int p = blockIdx.x; p < N_PANELS; p += GB) {
        const _Float16* abase = &Asw[(size_t)p * 4096 + lane * 8];
        f16x8 af[8];
#pragma unroll
        for (int kb = 0; kb < 8; ++kb)
            af[kb] = *(const f16x8*)&abase[kb * 512];

        f32x4 acc[4];
#pragma unroll
        for (int cp4 = 0; cp4 < 4; ++cp4) acc[cp4] = (f32x4){0.f, 0.f, 0.f, 0.f};
#pragma unroll
        for (int kb = 0; kb < 8; ++kb)
#pragma unroll
            for (int cp4 = 0; cp4 < 4; ++cp4)
                acc[cp4] = mfma_f16(af[kb], bf[cp4][kb], acc[cp4]);

        const int rq = 4 * (lane >> 4);
        if (MODE == 0) {
            _Float16* eb = (_Float16*)ebraw[w];
#pragma unroll
            for (int cp4 = 0; cp4 < 4; ++cp4)
#pragma unroll
                for (int rr = 0; rr < 4; ++rr)
                    eb[(rq + rr) * 72 + cp4 * 16 + lr] = (_Float16)acc[cp4][rr];
            _Float16* xp = (_Float16*)Cout;
#pragma unroll
            for (int it = 0; it < 2; ++it) {
                int rl = it * 8 + (lane >> 3);
                f16x8 v = *(const f16x8*)&eb[rl * 72 + (lane & 7) * 8];
                *(f16x8*)&xp[(size_t)(p * 16 + rl) * 256 + w * 64 + (lane & 7) * 8] = v;
            }
        } else {
            float* eb = (float*)ebraw[w];
#pragma unroll
            for (int cp4 = 0; cp4 < 4; ++cp4)
#pragma unroll
                for (int rr = 0; rr < 4; ++rr)
                    eb[(rq + rr) * 68 + cp4 * 16 + lr] = acc[cp4][rr] + bc[cp4];
            float* op = (float*)Cout;
#pragma unroll
            for (int it = 0; it < 4; ++it) {
                int rl = it * 4 + (lane >> 4);
                float4 v = *(const float4*)&eb[rl * 68 + lr * 4];
                *(float4*)&op[(size_t)(p * 16 + rl) * 256 + w * 64 + lr * 4] = v;
            }
        }
    }
}

// ---------------------------------------------------------------------------
// Aggregation: 8 nodes/block, 32 lanes/node, 8 features/lane, 4 gathers in
// flight; packed {src,norm} headers; writes fragment-swizzled f16 output.
// ---------------------------------------------------------------------------

__global__ __launch_bounds__(256) void agg_kernel(const _Float16* __restrict__ xt,
                                                  const int* __restrict__ row_ptr,
                                                  const int2* __restrict__ csr,
                                                  const float* __restrict__ bias,
                                                  _Float16* __restrict__ Asw) {
    const int g = threadIdx.x >> 5;
    const int l = threadIdx.x & 31;
    const int v = blockIdx.x * 8 + g;
    const int d0 = l * 8;

    const int s0 = row_ptr[v];
    const int s1 = row_ptr[v + 1];

    float acc[8] = {0.f, 0.f, 0.f, 0.f, 0.f, 0.f, 0.f, 0.f};

    int i = s0;
    for (; i + 4 <= s1; i += 4) {
        int2 hd[4];
#pragma unroll
        for (int u = 0; u < 4; ++u) hd[u] = csr[i + u];
        f16x8 val[4];
#pragma unroll
        for (int u = 0; u < 4; ++u)
            val[u] = *(const f16x8*)&xt[(size_t)hd[u].x * 256 + d0];
#pragma unroll
        for (int u = 0; u < 4; ++u) {
            float wv = __int_as_float(hd[u].y);
#pragma unroll
            for (int j = 0; j < 8; ++j)
                acc[j] += (float)val[u][j] * wv;
        }
    }
    {
        int rem = s1 - i;
        int2 hd[3];
#pragma unroll
        for (int u = 0; u < 3; ++u)
            hd[u] = (u < rem) ? csr[i + u] : make_int2(0, 0);
        f16x8 val[3];
#pragma unroll
        for (int u = 0; u < 3; ++u)
            val[u] = *(const f16x8*)&xt[(size_t)hd[u].x * 256 + d0];
#pragma unroll
        for (int u = 0; u < 3; ++u) {
            float wv = __int_as_float(hd[u].y);
#pragma unroll
            for (int j = 0; j < 8; ++j)
                acc[j] += (float)val[u][j] * wv;
        }
    }

    f16x8 o;
#pragma unroll
    for (int j = 0; j < 8; ++j) {
        float r = acc[j] + bias[d0 + j];
        r = r > 0.f ? r : 0.f;
        o[j] = (_Float16)r;
    }
    *(f16x8*)&Asw[swz(v, l)] = o;
}

// ---------------------------------------------------------------------------

extern "C" void kernel_launch(void* const* d_in, const int* in_sizes, int n_in,
                              void* d_out, int out_size, void* d_ws, size_t ws_size,
                              hipStream_t stream) {
    (void)in_sizes; (void)n_in; (void)out_size; (void)ws_size;
    const float* h5 = (const float*)d_in[0];
    const int*   ei = (const int*)d_in[1];
    const float* ew = (const float*)d_in[2];
    const float* W6 = (const float*)d_in[3];
    const float* b6 = (const float*)d_in[4];
    const float* W7 = (const float*)d_in[5];
    const float* b7 = (const float*)d_in[6];
    const float* Wp = (const float*)d_in[7];
    const float* bp = (const float*)d_in[8];
    float* out = (float*)d_out;

    char* ws = (char*)d_ws;
    size_t off = 0;
    auto alloc = [&](size_t bytes) -> void* {
        void* p = ws + off;
        off = (off + bytes + 255) & ~(size_t)255;
        return p;
    };

    // single zeroed region: pk_out | pk_in | cur
    char* zblk = (char*)alloc(ZBYTES);
    unsigned long long* pk_out = (unsigned long long*)zblk;
    unsigned long long* pk_in  = (unsigned long long*)(zblk + N_NODES * 8);
    int* cur = (int*)(zblk + N_NODES * 16);

    float* deg_out = (float*)alloc(N_NODES * 4);
    float* deg_in  = (float*)alloc(N_NODES * 4);
    int*   row_ptr = (int*)alloc((N_NODES + 1) * 4);
    int*   partial = (int*)alloc(SCAN_NB * 4);
    int2*  csr     = (int2*)alloc(N_EDGES * 8);
    _Float16* Bsw  = (_Float16*)alloc(3 * 65536 * 2);
    _Float16* Asw  = (_Float16*)alloc((size_t)N_NODES * 256 * 2);
    _Float16* xt   = (_Float16*)alloc((size_t)N_NODES * 256 * 2);

    const int Z16 = ZBYTES / 16;

    zero_kernel<<<(Z16 + 255) / 256, 256, 0, stream>>>((int4*)zblk, Z16);

    // deg (compact) ∥ wsplit ∥ asplit
    p1_kernel<<<DEGB + WB + AB, 256, 0, stream>>>(ei, ew, pk_out, pk_in,
                                                  W6, W7, Wp, Bsw, h5, Asw);

    scan1_kernel<<<SCAN_NB, 256, 0, stream>>>(pk_in, pk_out, deg_in, deg_out, partial);
    scan23_kernel<<<SCAN_NB, 256, 0, stream>>>(pk_in, partial, row_ptr);

    // fill (compact) ∥ gemm layer-1 (swizzled f16 A)
    p2_kernel<<<FILLB + GB, 256, 0, stream>>>(ei, ew, deg_out, deg_in, row_ptr, cur, csr,
                                              Asw, Bsw, xt);

    agg_kernel<<<N_NODES / 8, 256, 0, stream>>>(xt, row_ptr, csr, b6, Asw);
    gemm_f16<0><<<GB, 256, 0, stream>>>(Asw, Bsw + 65536, nullptr, xt);
    agg_kernel<<<N_NODES / 8, 256, 0, stream>>>(xt, row_ptr, csr, b7, Asw);
    gemm_f16<1><<<GB, 256, 0, stream>>>(Asw, Bsw + 2 * 65536, bp, out);
}